// Round 15
// baseline (240.378 us; speedup 1.0000x reference)
//
#include <hip/hip_runtime.h>
#include <hip/hip_bf16.h>
#include <math.h>

// Problem constants (PoseMixtureVAE)
#define N_BATCH 4096
#define FRAME   267
#define LATENT  32
#define HIDDEN  256
#define EXPERTS 6

typedef __hip_bfloat16 bf16;
typedef __bf16  bf16x8 __attribute__((ext_vector_type(8)));
typedef float   f32x4  __attribute__((ext_vector_type(4)));

__device__ __forceinline__ float eluf(float v) { return (v > 0.f) ? v : (expf(v) - 1.f); }

// ---------------------------------------------------------------------------
// Weight repack: src f32 slice -> dst bf16 [E][Kst][Mtot][32], packed by
// iteration index kt; segment mapping: packed kp=ktA*32+i, rel=kp-kBase,
// src row = srcRow0+rel (zero outside [0,Klen)). (R13/R14-validated core.)
// ---------------------------------------------------------------------------
struct WEnt { const float* src; bf16* dst;
              int Ksrc, Klen, srcRow0, kBase, kt0, nKt, Kst, M, Mtiles, Mtot, mOff, E, cum; };
struct WTab { WEnt e[18]; int total; };

__global__ __launch_bounds__(256) void wtr_kernel(WTab tab) {
    __shared__ float tbuf[32][33];
    const int tid = threadIdx.x, bid = blockIdx.x;
    int i = 0;
    while (i < 17 && bid >= tab.e[i + 1].cum) ++i;
    const WEnt en = tab.e[i];
    int t = bid - en.cum;
    const int perE = en.nKt * en.Mtiles;
    const int e = t / perE;  t -= e * perE;
    const int ktR = t / en.Mtiles, mt = t - ktR * en.Mtiles;
    const int ktA = en.kt0 + ktR;
    const int tx = tid & 31, ty = tid >> 5;
    #pragma unroll
    for (int i0 = 0; i0 < 32; i0 += 8) {
        const int kp  = ktA * 32 + i0 + ty;
        const int rel = kp - en.kBase;
        const int m   = mt * 32 + tx;
        float v = 0.f;
        if (rel >= 0 && rel < en.Klen && m < en.M)
            v = en.src[((size_t)e * en.Ksrc + en.srcRow0 + rel) * en.M + m];
        tbuf[i0 + ty][tx] = v;
    }
    __syncthreads();
    bf16* d = en.dst + ((size_t)(e * en.Kst + ktA) * en.Mtot + en.mOff + mt * 32) * 32;
    #pragma unroll
    for (int i0 = 0; i0 < 32; i0 += 8)
        d[(size_t)(i0 + ty) * 32 + tx] = __float2bfloat16(tbuf[tx][i0 + ty]);
}

// ---------------------------------------------------------------------------
// Mono kernel LDS A row layout (k-positions, bf16):
//   X: 0..287 (x, zero-pad), C: 288..575 (c), Z: 576..607 (z), H: 608..863
//   (reused: h1 -> h2 -> d1 -> d2). STRA = 872 (16B-aligned, non-pow2 banks).
// ---------------------------------------------------------------------------
#define STRA 872

__device__ __forceinline__ void seg_f32(bf16* sA, int kOff, const float* __restrict__ src,
                                        int cols, int alloc, int row0, int tid) {
    const int r = tid >> 5, c0 = (tid & 31) * 8;   // 32 rows x 32 thr/row
    const float* s = src + (size_t)(row0 + r) * cols;
    for (int kb = c0; kb < alloc; kb += 256) {
        bf16 tmp[8];
        #pragma unroll
        for (int j = 0; j < 8; ++j) tmp[j] = __float2bfloat16((kb + j < cols) ? s[kb + j] : 0.f);
        *(float4*)(sA + r * STRA + kOff + kb) = *(float4*)tmp;
    }
}

// Two-range RF=2 wave GEMM. B packed [E][N0+N1][Mtot][32] in iteration order;
// A read at LDS k-ranges (LK0,N0) then (LK1,N1). acc = sum_e co*(A@We + b_e).
template<int N0, int LK0, int N1, int LK1, int E>
__device__ __forceinline__ void wgemm(const bf16* __restrict__ Wt, int Mtot, int col,
    const bf16* __restrict__ sA, const float* __restrict__ bias, int M,
    const float* __restrict__ sCo, int ml, int quad, f32x4* acc)
{
    constexpr int KST = N0 + N1;
    acc[0] = (f32x4){0.f, 0.f, 0.f, 0.f};
    acc[1] = (f32x4){0.f, 0.f, 0.f, 0.f};
    const bf16* a0 = sA + ml * STRA + quad * 8;
    const bf16* a1 = sA + (16 + ml) * STRA + quad * 8;
    for (int e = 0; e < E; ++e) {
        f32x4 p0 = (f32x4){0.f, 0.f, 0.f, 0.f};
        f32x4 p1 = (f32x4){0.f, 0.f, 0.f, 0.f};
        const bf16* wp = Wt + ((size_t)e * KST * Mtot + col) * 32 + quad * 8;
        #pragma unroll
        for (int i = 0; i < N0; ++i) {
            const bf16x8 b = *(const bf16x8*)(wp + (size_t)i * Mtot * 32);
            p0 = __builtin_amdgcn_mfma_f32_16x16x32_bf16(*(const bf16x8*)(a0 + (LK0 + i) * 32), b, p0, 0, 0, 0);
            p1 = __builtin_amdgcn_mfma_f32_16x16x32_bf16(*(const bf16x8*)(a1 + (LK0 + i) * 32), b, p1, 0, 0, 0);
        }
        #pragma unroll
        for (int i = 0; i < N1; ++i) {
            const bf16x8 b = *(const bf16x8*)(wp + (size_t)(N0 + i) * Mtot * 32);
            p0 = __builtin_amdgcn_mfma_f32_16x16x32_bf16(*(const bf16x8*)(a0 + (LK1 + i) * 32), b, p0, 0, 0, 0);
            p1 = __builtin_amdgcn_mfma_f32_16x16x32_bf16(*(const bf16x8*)(a1 + (LK1 + i) * 32), b, p1, 0, 0, 0);
        }
        const float bv = (bias && col < M) ? bias[(size_t)e * M + col] : 0.f;
        #pragma unroll
        for (int rg = 0; rg < 4; ++rg) {
            const float s0 = sCo ? sCo[e * 32 + quad * 4 + rg]      : 1.f;
            const float s1 = sCo ? sCo[e * 32 + 16 + quad * 4 + rg] : 1.f;
            acc[0][rg] += s0 * (p0[rg] + bv);
            acc[1][rg] += s1 * (p1[rg] + bv);
        }
    }
}

__device__ __forceinline__ void store_H(bf16* sA, int col, int quad, const f32x4* acc, bool act) {
    #pragma unroll
    for (int rf = 0; rf < 2; ++rf)
        #pragma unroll
        for (int rg = 0; rg < 4; ++rg) {
            float v = acc[rf][rg];
            if (act) v = eluf(v);
            sA[(16 * rf + quad * 4 + rg) * STRA + 608 + col] = __float2bfloat16(v);
        }
}

struct MonoArgs {
    const float *x, *c, *eps;
    const float *enc_b1, *enc_b2, *enc_bmu, *enc_blv, *g_b0, *g_b1, *g_b2, *b0, *b1, *b2;
    float *out_layer, *out_mu, *out_lv;
    const bf16 *Wt_e1, *Wt_e2, *Wt_ml, *Wt_g0, *Wt_g1, *Wt_g2, *Wt_w0, *Wt_w1, *Wt_w2;
};

// ---------------------------------------------------------------------------
// One block = 32 batch rows through the ENTIRE network (row-local => no
// cross-block sync). 1024 threads = 16 waves (4/SIMD); wave w owns cols
// 16w..16w+15 of every 256-col stage; RF=2 row-fragments.
// ---------------------------------------------------------------------------
__global__ __launch_bounds__(1024) void mono_kernel(MonoArgs a) {
    __shared__ bf16 sA[32 * STRA];      // 55808 B
    __shared__ char scr[9216];          // sML / (sG1|sG2) / sLg+sCo overlays
    const int tid = threadIdx.x;
    const int row0 = blockIdx.x * 32;
    const int w = tid >> 6, lane = tid & 63, ml = lane & 15, quad = lane >> 4;
    const int colg = 16 * w + ml;       // 0..255

    // stage X and C (f32 -> bf16, zero-padded)
    seg_f32(sA, 0,   a.x, FRAME, 288, row0, tid);
    seg_f32(sA, 288, a.c, FRAME, 288, row0, tid);
    __syncthreads();

    f32x4 acc[2];
    // S1: h1 = elu([x|c] @ W1 + b1) -> H
    wgemm<18, 0, 0, 0, 1>(a.Wt_e1, 256, colg, sA, a.enc_b1, 256, nullptr, ml, quad, acc);
    store_H(sA, colg, quad, acc, true);     // H disjoint from X/C reads
    __syncthreads();

    // S2: h2 = elu([x|h1] @ W2 + b2) -> H
    wgemm<9, 0, 8, 19, 1>(a.Wt_e2, 256, colg, sA, a.enc_b2, 256, nullptr, ml, quad, acc);
    __syncthreads();                        // all h1 reads done
    store_H(sA, colg, quad, acc, true);
    __syncthreads();

    // S3: mu|lv = [x|h2] @ Wml + bcat (waves 0..3, M=64) -> sML
    float* sML = (float*)scr;
    if (w < 4) {
        f32x4 am[2];
        wgemm<9, 0, 8, 19, 1>(a.Wt_ml, 64, colg, sA, nullptr, 64, nullptr, ml, quad, am);
        const float bv = (colg < 32) ? a.enc_bmu[colg] : a.enc_blv[colg - 32];
        #pragma unroll
        for (int rf = 0; rf < 2; ++rf)
            #pragma unroll
            for (int rg = 0; rg < 4; ++rg)
                sML[(16 * rf + quad * 4 + rg) * 64 + colg] = am[rf][rg] + bv;
    }
    __syncthreads();

    // z = mu + eps*exp(0.5*lv) -> Z region; mu/lv -> d_out (f32)
    {
        const int r = tid >> 5, l = tid & 31;
        const float m  = sML[r * 64 + l];
        const float lv = sML[r * 64 + 32 + l];
        const int gi = (row0 + r) * LATENT + l;
        a.out_mu[gi] = m; a.out_lv[gi] = lv;
        sA[r * STRA + 576 + l] = __float2bfloat16(m + a.eps[gi] * expf(0.5f * lv));
    }
    __syncthreads();

    // gate g1 = elu([c|z] @ g0) (waves 0..3) -> sG1
    bf16* sG1 = (bf16*)scr;
    bf16* sG2 = (bf16*)(scr + 4608);
    if (w < 4) {
        f32x4 ag[2];
        wgemm<9, 9, 1, 18, 1>(a.Wt_g0, 64, colg, sA, a.g_b0, 64, nullptr, ml, quad, ag);
        #pragma unroll
        for (int rf = 0; rf < 2; ++rf)
            #pragma unroll
            for (int rg = 0; rg < 4; ++rg)
                sG1[(16 * rf + quad * 4 + rg) * 72 + colg] = __float2bfloat16(eluf(ag[rf][rg]));
    }
    __syncthreads();

    // g2 = elu(g1 @ g1w) (waves 0..3): A = sG1 stride 72
    if (w < 4) {
        f32x4 p0 = (f32x4){0.f, 0.f, 0.f, 0.f};
        f32x4 p1 = (f32x4){0.f, 0.f, 0.f, 0.f};
        const bf16* wp = a.Wt_g1 + (size_t)colg * 32 + quad * 8;
        #pragma unroll
        for (int ks = 0; ks < 2; ++ks) {
            const bf16x8 b  = *(const bf16x8*)(wp + (size_t)ks * 64 * 32);
            const bf16x8 a0 = *(const bf16x8*)(sG1 + ml * 72 + ks * 32 + quad * 8);
            const bf16x8 a1 = *(const bf16x8*)(sG1 + (16 + ml) * 72 + ks * 32 + quad * 8);
            p0 = __builtin_amdgcn_mfma_f32_16x16x32_bf16(a0, b, p0, 0, 0, 0);
            p1 = __builtin_amdgcn_mfma_f32_16x16x32_bf16(a1, b, p1, 0, 0, 0);
        }
        const float bv = a.g_b1[colg];
        #pragma unroll
        for (int rf = 0; rf < 2; ++rf)
            #pragma unroll
            for (int rg = 0; rg < 4; ++rg)
                sG2[(16 * rf + quad * 4 + rg) * 72 + colg] =
                    __float2bfloat16(eluf(((rf == 0) ? p0[rg] : p1[rg]) + bv));
    }
    __syncthreads();

    // logits (wave 0, M=6, Mtot=32) -> sLg (overlays dead sG1)
    float* sLg = (float*)scr;
    if (w == 0) {
        f32x4 p0 = (f32x4){0.f, 0.f, 0.f, 0.f};
        f32x4 p1 = (f32x4){0.f, 0.f, 0.f, 0.f};
        const bf16* wp = a.Wt_g2 + (size_t)ml * 32 + quad * 8;
        #pragma unroll
        for (int ks = 0; ks < 2; ++ks) {
            const bf16x8 b  = *(const bf16x8*)(wp + (size_t)ks * 32 * 32);
            const bf16x8 a0 = *(const bf16x8*)(sG2 + ml * 72 + ks * 32 + quad * 8);
            const bf16x8 a1 = *(const bf16x8*)(sG2 + (16 + ml) * 72 + ks * 32 + quad * 8);
            p0 = __builtin_amdgcn_mfma_f32_16x16x32_bf16(a0, b, p0, 0, 0, 0);
            p1 = __builtin_amdgcn_mfma_f32_16x16x32_bf16(a1, b, p1, 0, 0, 0);
        }
        const float bv = (ml < EXPERTS) ? a.g_b2[ml] : 0.f;
        #pragma unroll
        for (int rg = 0; rg < 4; ++rg) {
            sLg[(quad * 4 + rg) * 16 + ml]      = p0[rg] + bv;
            sLg[(16 + quad * 4 + rg) * 16 + ml] = p1[rg] + bv;
        }
    }
    __syncthreads();

    // softmax -> sCo (overlays dead sG1 bytes 2048..2815)
    float* sCo = (float*)(scr + 2048);
    if (tid < 32) {
        float v[EXPERTS];
        float m = -1e30f;
        #pragma unroll
        for (int i = 0; i < EXPERTS; ++i) { v[i] = sLg[tid * 16 + i]; m = fmaxf(m, v[i]); }
        float s = 0.f;
        #pragma unroll
        for (int i = 0; i < EXPERTS; ++i) { v[i] = expf(v[i] - m); s += v[i]; }
        const float inv = 1.f / s;
        #pragma unroll
        for (int i = 0; i < EXPERTS; ++i) sCo[i * 32 + tid] = v[i] * inv;
    }
    __syncthreads();

    // S4: d1 = elu(moe([c|z], w0, b0)) -> H (h2 dead)
    wgemm<9, 9, 1, 18, EXPERTS>(a.Wt_w0, 256, colg, sA, a.b0, 256, sCo, ml, quad, acc);
    store_H(sA, colg, quad, acc, true);
    __syncthreads();

    // S5: d2 = elu(moe([z|d1], w1, b1)) -> H
    wgemm<1, 18, 8, 19, EXPERTS>(a.Wt_w1, 256, colg, sA, a.b1, 256, sCo, ml, quad, acc);
    __syncthreads();
    store_H(sA, colg, quad, acc, true);
    __syncthreads();

    // S6: out = moe([z|d2], w2, b2) -> d_out (f32), M=267 (tail by wave 0)
    wgemm<1, 18, 8, 19, EXPERTS>(a.Wt_w2, 320, colg, sA, a.b2, FRAME, sCo, ml, quad, acc);
    #pragma unroll
    for (int rf = 0; rf < 2; ++rf)
        #pragma unroll
        for (int rg = 0; rg < 4; ++rg)
            if (colg < FRAME)
                a.out_layer[(size_t)(row0 + 16 * rf + quad * 4 + rg) * FRAME + colg] = acc[rf][rg];
    if (w == 0) {
        f32x4 a2[2];
        const int col2 = 256 + ml;
        wgemm<1, 18, 8, 19, EXPERTS>(a.Wt_w2, 320, col2, sA, a.b2, FRAME, sCo, ml, quad, a2);
        #pragma unroll
        for (int rf = 0; rf < 2; ++rf)
            #pragma unroll
            for (int rg = 0; rg < 4; ++rg)
                if (col2 < FRAME)
                    a.out_layer[(size_t)(row0 + 16 * rf + quad * 4 + rg) * FRAME + col2] = a2[rf][rg];
    }
}

// ---------------------------------------------------------------------------
extern "C" void kernel_launch(void* const* d_in, const int* in_sizes, int n_in,
                              void* d_out, int out_size, void* d_ws, size_t ws_size,
                              hipStream_t stream) {
    MonoArgs a;
    a.x       = (const float*)d_in[0];
    a.c       = (const float*)d_in[1];
    a.eps     = (const float*)d_in[2];
    const float* enc_w1  = (const float*)d_in[3];
    a.enc_b1  = (const float*)d_in[4];
    const float* enc_w2  = (const float*)d_in[5];
    a.enc_b2  = (const float*)d_in[6];
    const float* enc_wmu = (const float*)d_in[7];
    a.enc_bmu = (const float*)d_in[8];
    const float* enc_wlv = (const float*)d_in[9];
    a.enc_blv = (const float*)d_in[10];
    const float* g_w0    = (const float*)d_in[11];
    a.g_b0    = (const float*)d_in[12];
    const float* g_w1    = (const float*)d_in[13];
    a.g_b1    = (const float*)d_in[14];
    const float* g_w2    = (const float*)d_in[15];
    a.g_b2    = (const float*)d_in[16];
    const float* w0      = (const float*)d_in[17];
    a.b0      = (const float*)d_in[18];
    const float* w1      = (const float*)d_in[19];
    a.b1      = (const float*)d_in[20];
    const float* w2      = (const float*)d_in[21];
    a.b2      = (const float*)d_in[22];

    a.out_layer = (float*)d_out;
    a.out_mu    = a.out_layer + (size_t)N_BATCH * FRAME;
    a.out_lv    = a.out_mu    + (size_t)N_BATCH * LATENT;

    // ---- workspace: repacked weights only ----
    char* p = (char*)d_ws;
    bf16* Wt_e1 = (bf16*)p;  p += (size_t)18 * 256 * 32 * 2;
    bf16* Wt_e2 = (bf16*)p;  p += (size_t)17 * 256 * 32 * 2;
    bf16* Wt_ml = (bf16*)p;  p += (size_t)17 * 64 * 32 * 2;
    bf16* Wt_g0 = (bf16*)p;  p += (size_t)10 * 64 * 32 * 2;
    bf16* Wt_g1 = (bf16*)p;  p += (size_t)2 * 64 * 32 * 2;
    bf16* Wt_g2 = (bf16*)p;  p += (size_t)2 * 32 * 32 * 2;
    bf16* Wt_w0 = (bf16*)p;  p += (size_t)EXPERTS * 10 * 256 * 32 * 2;
    bf16* Wt_w1 = (bf16*)p;  p += (size_t)EXPERTS * 9 * 256 * 32 * 2;
    bf16* Wt_w2 = (bf16*)p;  p += (size_t)EXPERTS * 9 * 320 * 32 * 2;
    a.Wt_e1 = Wt_e1; a.Wt_e2 = Wt_e2; a.Wt_ml = Wt_ml; a.Wt_g0 = Wt_g0;
    a.Wt_g1 = Wt_g1; a.Wt_g2 = Wt_g2; a.Wt_w0 = Wt_w0; a.Wt_w1 = Wt_w1; a.Wt_w2 = Wt_w2;

    WTab tab;
    int cum = 0, n = 0;
    auto add = [&](const float* src, bf16* dst, int Ksrc, int Klen, int srcRow0,
                   int kBase, int kt0, int nKt, int Kst, int M, int Mtot, int mOff, int E) {
        const int Mtiles = (M + 31) / 32;
        tab.e[n] = {src, dst, Ksrc, Klen, srcRow0, kBase, kt0, nKt, Kst, M, Mtiles, Mtot, mOff, E, cum};
        cum += E * nKt * Mtiles;
        ++n;
    };
    //   src      dst    Ksrc Klen row0 kBase kt0 nKt Kst  M   Mtot mOff E
    add(enc_w1,  Wt_e1, 534, 267, 0,   0,    0,  9,  18, 256, 256, 0,  1);   // x part
    add(enc_w1,  Wt_e1, 534, 267, 267, 288,  9,  9,  18, 256, 256, 0,  1);   // c part
    add(enc_w2,  Wt_e2, 523, 267, 0,   0,    0,  9,  17, 256, 256, 0,  1);   // x
    add(enc_w2,  Wt_e2, 523, 256, 267, 288,  9,  8,  17, 256, 256, 0,  1);   // h1
    add(enc_wmu, Wt_ml, 523, 267, 0,   0,    0,  9,  17, 32,  64,  0,  1);
    add(enc_wmu, Wt_ml, 523, 256, 267, 288,  9,  8,  17, 32,  64,  0,  1);
    add(enc_wlv, Wt_ml, 523, 267, 0,   0,    0,  9,  17, 32,  64,  32, 1);
    add(enc_wlv, Wt_ml, 523, 256, 267, 288,  9,  8,  17, 32,  64,  32, 1);
    add(g_w0,    Wt_g0, 299, 267, 32,  0,    0,  9,  10, 64,  64,  0,  1);   // c part (A at C)
    add(g_w0,    Wt_g0, 299, 32,  0,   288,  9,  1,  10, 64,  64,  0,  1);   // z part (A at Z)
    add(g_w1,    Wt_g1, 64,  64,  0,   0,    0,  2,  2,  64,  64,  0,  1);
    add(g_w2,    Wt_g2, 64,  64,  0,   0,    0,  2,  2,  6,   32,  0,  1);
    add(w0,      Wt_w0, 299, 267, 32,  0,    0,  9,  10, 256, 256, 0,  EXPERTS);
    add(w0,      Wt_w0, 299, 32,  0,   288,  9,  1,  10, 256, 256, 0,  EXPERTS);
    add(w1,      Wt_w1, 288, 32,  0,   0,    0,  1,  9,  256, 256, 0,  EXPERTS); // z
    add(w1,      Wt_w1, 288, 256, 32,  32,   1,  8,  9,  256, 256, 0,  EXPERTS); // d1
    add(w2,      Wt_w2, 288, 32,  0,   0,    0,  1,  9,  267, 320, 0,  EXPERTS);
    add(w2,      Wt_w2, 288, 256, 32,  32,   1,  8,  9,  267, 320, 0,  EXPERTS);
    tab.total = cum;   // 1738

    wtr_kernel<<<dim3(cum), dim3(256), 0, stream>>>(tab);
    mono_kernel<<<dim3(N_BATCH / 32), dim3(1024), 0, stream>>>(a);
}